// Round 1
// baseline (854.547 us; speedup 1.0000x reference)
//
#include <hip/hip_runtime.h>

// Problem constants (from reference)
#define TOKENS  8192
#define IN_DIM  4096
#define OUT_DIM 4096
#define NUM_LUT 2
#define LUT_SIZE 16
#define VEC 8
#define GROUPS 512   // IN/VEC

typedef __bf16 bf16x8 __attribute__((ext_vector_type(8)));
typedef float  f32x4  __attribute__((ext_vector_type(4)));

__device__ __forceinline__ unsigned short f2bf(float f) {
    unsigned u = __float_as_uint(f);
    u += 0x7fffu + ((u >> 16) & 1u);   // round-to-nearest-even
    return (unsigned short)(u >> 16);
}

// ---------------------------------------------------------------------------
// Kernel 1: cast x (fp32) -> bf16, 8 elements/thread, fully vectorized
// ---------------------------------------------------------------------------
__global__ __launch_bounds__(256) void cast_x_bf16(const float* __restrict__ x,
                                                   unsigned short* __restrict__ y) {
    size_t i = ((size_t)blockIdx.x * 256 + threadIdx.x) * 8;
    float4 a = *(const float4*)(x + i);
    float4 b = *(const float4*)(x + i + 4);
    uint4 o;
    o.x = (unsigned)f2bf(a.x) | ((unsigned)f2bf(a.y) << 16);
    o.y = (unsigned)f2bf(a.z) | ((unsigned)f2bf(a.w) << 16);
    o.z = (unsigned)f2bf(b.x) | ((unsigned)f2bf(b.y) << 16);
    o.w = (unsigned)f2bf(b.z) | ((unsigned)f2bf(b.w) << 16);
    *(uint4*)(y + i) = o;
}

// ---------------------------------------------------------------------------
// Kernel 2: weight build.  W[o, g*8+v] = sum_n sum_k softmax(logits[n,o,g,:])[k] * luts[n,g,k,v]
// Block = 256 threads = 16 o x 16 g.  LUTs for the block's 16 g staged in LDS
// with padded stride 132 floats (132%32==4 -> max 2-way bank aliasing, free).
// ---------------------------------------------------------------------------
__global__ __launch_bounds__(256) void weight_kernel(const float* __restrict__ logits,
                                                     const float* __restrict__ luts,
                                                     unsigned short* __restrict__ W) {
    __shared__ float lsm[NUM_LUT * 16 * 132];   // [n][g_local][k*8+v], stride 132
    const int t  = threadIdx.x;
    const int g0 = blockIdx.x * 16;
    const int o0 = blockIdx.y * 16;

    // cooperative LUT load: per n, 16 g x 128 floats = 2048 floats; 8 floats/thread
    {
        const int gl  = t >> 4;          // 0..15
        const int idx = (t & 15) * 8;    // 0..120
        for (int n = 0; n < NUM_LUT; ++n) {
            const float4* s = (const float4*)(luts + (size_t)n * GROUPS * LUT_SIZE * VEC
                                              + (size_t)(g0 + gl) * (LUT_SIZE * VEC) + idx);
            float4* d = (float4*)(lsm + n * (16 * 132) + gl * 132 + idx);
            d[0] = s[0];
            d[1] = s[1];
        }
    }
    __syncthreads();

    const int gl = t & 15;
    const int ol = t >> 4;
    const int o  = o0 + ol;
    const int g  = g0 + gl;

    float4 wa = make_float4(0.f, 0.f, 0.f, 0.f);
    float4 wb = make_float4(0.f, 0.f, 0.f, 0.f);

    for (int n = 0; n < NUM_LUT; ++n) {
        const float* lg = logits + (((size_t)n * OUT_DIM + o) * GROUPS + g) * LUT_SIZE;
        float v[16];
        ((float4*)v)[0] = ((const float4*)lg)[0];
        ((float4*)v)[1] = ((const float4*)lg)[1];
        ((float4*)v)[2] = ((const float4*)lg)[2];
        ((float4*)v)[3] = ((const float4*)lg)[3];

        float m = v[0];
        #pragma unroll
        for (int k = 1; k < 16; ++k) m = fmaxf(m, v[k]);
        float e[16];
        float s = 0.f;
        #pragma unroll
        for (int k = 0; k < 16; ++k) { e[k] = __expf(v[k] - m); s += e[k]; }
        const float rs = 1.0f / s;

        const float4* lut4 = (const float4*)(lsm + n * (16 * 132) + gl * 132);
        #pragma unroll
        for (int k = 0; k < 16; ++k) {
            const float sw = e[k] * rs;
            float4 a = lut4[2 * k];
            float4 b = lut4[2 * k + 1];
            wa.x += sw * a.x; wa.y += sw * a.y; wa.z += sw * a.z; wa.w += sw * a.w;
            wb.x += sw * b.x; wb.y += sw * b.y; wb.z += sw * b.z; wb.w += sw * b.w;
        }
    }

    uint4 p;
    p.x = (unsigned)f2bf(wa.x) | ((unsigned)f2bf(wa.y) << 16);
    p.y = (unsigned)f2bf(wa.z) | ((unsigned)f2bf(wa.w) << 16);
    p.z = (unsigned)f2bf(wb.x) | ((unsigned)f2bf(wb.y) << 16);
    p.w = (unsigned)f2bf(wb.z) | ((unsigned)f2bf(wb.w) << 16);
    *(uint4*)(W + (size_t)o * IN_DIM + g * VEC) = p;
}

// ---------------------------------------------------------------------------
// Kernel 3: C[M,N] = A[M,K] * B[N,K]^T + bias[N]   (bf16 in, fp32 out)
// m97-style: 128x128 tile, BK=32, 4 waves (2x2), 4x4 16x16x32 MFMAs per wave,
// global_load_lds width=16 staging.
// ---------------------------------------------------------------------------
#define BM 128
#define BN 128
#define BK 32

__global__ __launch_bounds__(256) void gemm_bt(const __bf16* __restrict__ A,
                                               const __bf16* __restrict__ B,
                                               const float* __restrict__ bias,
                                               float* __restrict__ C) {
    __shared__ __align__(16) __bf16 As[BM * BK];
    __shared__ __align__(16) __bf16 Bs[BN * BK];

    const int tid  = threadIdx.x;
    const int bn   = blockIdx.x;
    const int bm   = blockIdx.y;
    const int rowBase = bm * BM;
    const int colBase = bn * BN;
    const int lane  = tid & 63;
    const int wave  = tid >> 6;
    const int waveM = wave >> 1;
    const int waveN = wave & 1;
    const int lcol  = lane & 15;
    const int quad  = lane >> 4;

    f32x4 acc[4][4] = {};

    // staging: thread t loads 16B; row = t/4 (0..63), col16 = t%4; second load at row+64
    const int sRow = tid >> 2;
    const int sCol = (tid & 3) * 8;
    const __bf16* Ap = A + (size_t)(rowBase + sRow) * IN_DIM + sCol;
    const __bf16* Bp = B + (size_t)(colBase + sRow) * IN_DIM + sCol;
    __bf16* AsD = As + tid * 8;   // contiguous: lane i of wave w -> base(w*1024B) + i*16B
    __bf16* BsD = Bs + tid * 8;

    for (int kt = 0; kt < IN_DIM; kt += BK) {
        __builtin_amdgcn_global_load_lds((const __attribute__((address_space(1))) void*)Ap,
                                         (__attribute__((address_space(3))) void*)AsD, 16, 0, 0);
        __builtin_amdgcn_global_load_lds((const __attribute__((address_space(1))) void*)(Ap + (size_t)64 * IN_DIM),
                                         (__attribute__((address_space(3))) void*)(AsD + 64 * BK), 16, 0, 0);
        __builtin_amdgcn_global_load_lds((const __attribute__((address_space(1))) void*)Bp,
                                         (__attribute__((address_space(3))) void*)BsD, 16, 0, 0);
        __builtin_amdgcn_global_load_lds((const __attribute__((address_space(1))) void*)(Bp + (size_t)64 * IN_DIM),
                                         (__attribute__((address_space(3))) void*)(BsD + 64 * BK), 16, 0, 0);
        Ap += BK;
        Bp += BK;
        __syncthreads();

        bf16x8 af[4], bfr[4];
        #pragma unroll
        for (int i = 0; i < 4; ++i)
            af[i] = *(const bf16x8*)&As[(waveM * 64 + i * 16 + lcol) * BK + quad * 8];
        #pragma unroll
        for (int j = 0; j < 4; ++j)
            bfr[j] = *(const bf16x8*)&Bs[(waveN * 64 + j * 16 + lcol) * BK + quad * 8];

        #pragma unroll
        for (int i = 0; i < 4; ++i)
            #pragma unroll
            for (int j = 0; j < 4; ++j)
                acc[i][j] = __builtin_amdgcn_mfma_f32_16x16x32_bf16(af[i], bfr[j], acc[i][j], 0, 0, 0);

        __syncthreads();
    }

    // epilogue: C/D layout col = lane&15, row = quad*4 + reg
    #pragma unroll
    for (int j = 0; j < 4; ++j) {
        const int col = colBase + waveN * 64 + j * 16 + lcol;
        const float bv = bias[col];
        #pragma unroll
        for (int i = 0; i < 4; ++i) {
            const int row0 = rowBase + waveM * 64 + i * 16 + quad * 4;
            #pragma unroll
            for (int r = 0; r < 4; ++r) {
                C[(size_t)(row0 + r) * OUT_DIM + col] = acc[i][j][r] + bv;
            }
        }
    }
}

// ---------------------------------------------------------------------------
// Launch
// ---------------------------------------------------------------------------
extern "C" void kernel_launch(void* const* d_in, const int* in_sizes, int n_in,
                              void* d_out, int out_size, void* d_ws, size_t ws_size,
                              hipStream_t stream) {
    const float* x      = (const float*)d_in[0];
    const float* logits = (const float*)d_in[1];
    const float* luts   = (const float*)d_in[2];
    const float* bias   = (const float*)d_in[3];
    float* out = (float*)d_out;

    // workspace layout: x_bf16 (64 MB) | W_bf16 (32 MB)
    unsigned short* xb = (unsigned short*)d_ws;
    unsigned short* wb = xb + (size_t)TOKENS * IN_DIM;

    cast_x_bf16<<<(TOKENS * IN_DIM) / (256 * 8), 256, 0, stream>>>(x, xb);

    weight_kernel<<<dim3(GROUPS / 16, OUT_DIM / 16), 256, 0, stream>>>(logits, luts, wb);

    gemm_bt<<<dim3(OUT_DIM / BN, TOKENS / BM), 256, 0, stream>>>(
        (const __bf16*)xb, (const __bf16*)wb, bias, out);
}